// Round 12
// baseline (416.572 us; speedup 1.0000x reference)
//
#include <hip/hip_runtime.h>
#include <hip/hip_bf16.h>

// Classifier_69818988363910:
//   F = mean_pool_J30(relu(x @ W1^T))                [2000, 2048]
//   logits = F @ (Wlin[:, :2048]+Wlin[:, 2048:])^T   [2000, 1000]
// (y, W2 are dead per the reference's own bug; features2 == features)

typedef __attribute__((ext_vector_type(4))) float f32x4;
typedef __attribute__((ext_vector_type(8))) short short8;
typedef __attribute__((ext_vector_type(2))) unsigned long long u64x2;

__device__ __forceinline__ unsigned short f2bf(float f) {
  unsigned int u = __float_as_uint(f);
  unsigned int r = (u + 0x7fffu + ((u >> 16) & 1u)) >> 16;
  return (unsigned short)r;
}

__device__ __forceinline__ unsigned long long pack4(f32x4 v) {
  return (unsigned long long)f2bf(v.x)
       | ((unsigned long long)f2bf(v.y) << 16)
       | ((unsigned long long)f2bf(v.z) << 32)
       | ((unsigned long long)f2bf(v.w) << 48);
}

__device__ __forceinline__ void gload_lds16(const unsigned short* gp, unsigned short* lp) {
  __builtin_amdgcn_global_load_lds((const __attribute__((address_space(1))) void*)gp,
                                   (__attribute__((address_space(3))) void*)lp, 16, 0, 0);
}

__global__ void cvt_f32_bf16(const float* __restrict__ src,
                             unsigned short* __restrict__ dst, int n4) {
  int i = blockIdx.x * 256 + threadIdx.x;
  if (i >= n4) return;
  f32x4 v = *(const f32x4*)(src + (size_t)i * 4);
  *(unsigned long long*)(dst + (size_t)i * 4) = pack4(v);
}

__global__ void prep_wsum(const float* __restrict__ wlin,
                          unsigned short* __restrict__ dst) {
  int i = blockIdx.x * 256 + threadIdx.x;
  if (i >= 1000 * 512) return;
  int c = i >> 9, f4 = i & 511;
  const float* p0 = wlin + (size_t)c * 4096 + f4 * 4;
  f32x4 a = *(const f32x4*)p0;
  f32x4 b = *(const f32x4*)(p0 + 2048);
  f32x4 s = a + b;
  *(unsigned long long*)(dst + (size_t)c * 2048 + f4 * 4) = pack4(s);
}

// ---------------------------------------------------------------------------
// GEMM1: 256x256 tile, 4-Q schedule (one barrier per K-half, both IH halves).
// A is read DIRECTLY from x (f32) and converted in-kernel: per Q, AWRITE
// packs the pending registers (loaded one FULL Q ~1350cyc earlier — covers
// ~900cyc HBM latency; R9's 1-phase distance was the regression cause) into
// the swizzled LDS slot via 2 ds_write_b128. B stays global_load_lds with
// pre-swizzled source. No hand vmcnt in the loop: the compiler's vmcnt wait
// at each Q's AWRITE (pa use) drains all prior-Q loads (>=1Q old, landed) —
// it is also the B-stage drain. lgkm0 before every barrier makes A ds_writes
// visible across waves. Slot ledger: each slot is overwritten exactly one
// barrier after its last reader (Q0 reads (0,0) / writes (1,1)+stages B(1,1);
// Q1 reads (0,1) / writes+stages (0,0)'; Q2 reads (1,0) / (0,1)'; Q3 reads
// (1,1) / (1,0)').
// ---------------------------------------------------------------------------
#define WAITV(n) asm volatile("s_waitcnt vmcnt(" #n ")" ::: "memory")
#define LGKM0()  asm volatile("s_waitcnt lgkmcnt(0)" ::: "memory")
#define CFENCE() asm volatile("" ::: "memory")

__global__ __launch_bounds__(512, 2)
void gemm256_pool_fA(const float* __restrict__ X,
                     const unsigned short* __restrict__ B,
                     unsigned short* __restrict__ feat,
                     int Mv, int K) {
  __shared__ __align__(16) unsigned short smem[65536];  // 128 KB

  const int tid = threadIdx.x;
  const int lane = tid & 63;
  const int w = tid >> 6;          // 0..7
  const int wr = w >> 2;           // 0..1  (M half)
  const int wc = w & 3;            // 0..3  (N quarter)

  // XCD-chunked bijective swizzle: 2000 blocks, 8 XCDs, 250 each.
  const int bid = blockIdx.x;
  const int swz = (bid & 7) * 250 + (bid >> 3);
  const int by = swz >> 3;         // 0..249  M-block
  const int bx = swz & 7;          // 0..7    N-block
  const int bm0 = by * 240;
  const int bn0 = bx * 256;
  const int NT2 = K >> 6;          // K-steps of 64 (=16)
  const int NI = NT2 >> 1;         // iterations (=8)

  // rows covered by this thread for staging
  int rA0 = bm0 + w * 32 + 0 + (lane >> 2);  if (rA0 >= Mv) rA0 = Mv - 1;
  int rA1 = bm0 + w * 32 + 16 + (lane >> 2); if (rA1 >= Mv) rA1 = Mv - 1;
  const int rB0 = bn0 + w * 32 + 0 + (lane >> 2);
  const int rB1 = bn0 + w * 32 + 16 + (lane >> 2);

  // A: natural k offset (we swizzle at the ds_write); B: pre-swizzled source
  const int kslot_a = (lane & 3) * 8;
  const int kslot_b = (((lane & 3) ^ ((lane >> 3) & 3)) * 8);
  const float* gxA0 = X + (size_t)rA0 * K + kslot_a;
  const float* gxA1 = X + (size_t)rA1 * K + kslot_a;
  const unsigned short* gB0 = B + (size_t)rB0 * K + kslot_b;
  const unsigned short* gB1 = B + (size_t)rB1 * K + kslot_b;

  // A ds_write address: row*32 shorts + swizzled chunk ((lane&3)^((row>>1)&3))
  unsigned short* awp = smem + (w * 32 + (lane >> 2)) * 32 +
                        (((lane & 3) ^ ((lane >> 3) & 3)) * 8);

  f32x4 pa0, pa1, pa2, pa3;        // pending A half-tile (f32), 1-Q prefetch

#define KOF(tt) ((size_t)(((tt) < NT2) ? (tt) : (NT2 - 1)) * 64)
#define AISSUE(ko) do {                                                  \
    pa0 = *(const f32x4*)(gxA0 + (ko));                                  \
    pa1 = *(const f32x4*)(gxA0 + (ko) + 4);                              \
    pa2 = *(const f32x4*)(gxA1 + (ko));                                  \
    pa3 = *(const f32x4*)(gxA1 + (ko) + 4);                              \
  } while (0)
#define AWRITE(S, KS) do {                                               \
    unsigned short* _p = awp + ((S)*2+(KS))*8192;                        \
    *(u64x2*)_p         = (u64x2){pack4(pa0), pack4(pa1)};               \
    *(u64x2*)(_p + 512) = (u64x2){pack4(pa2), pack4(pa3)};               \
  } while (0)
#define STAGE_B(tt, S, KS) do {                                          \
    const size_t _ko = KOF(tt) + (KS) * 32;                              \
    gload_lds16(gB0 + _ko, smem + 32768 + ((S)*2+(KS))*8192 + w * 1024); \
    gload_lds16(gB1 + _ko, smem + 32768 + ((S)*2+(KS))*8192 + w * 1024 + 512); \
  } while (0)

  f32x4 acc[8][4];
#pragma unroll
  for (int i = 0; i < 8; ++i)
#pragma unroll
    for (int j = 0; j < 4; ++j) acc[i][j] = (f32x4){0.f, 0.f, 0.f, 0.f};

  // fragment reads: row R (stride 32 shorts), phys chunk = q ^ ((fr>>1)&3)
  const int fr = lane & 15;
  const int qa8 = (((lane >> 4) ^ ((fr >> 1) & 3)) * 8);
#define LDA(S, KS, I) (*(const short8*)(smem + ((S)*2+(KS))*8192 +       \
    (wr * 128 + (I) * 16 + fr) * 32 + qa8))
#define LDB(S, KS, J) (*(const short8*)(smem + 32768 + ((S)*2+(KS))*8192 + \
    (wc * 64 + (J) * 16 + fr) * 32 + qa8))

  // one Q's compute: 12 ds_reads + 32 MFMA over both IH halves of (S,KS)
#define QCOMPUTE(S, KS) do {                                             \
    short8 bfr[4], afr[4];                                               \
    _Pragma("unroll") for (int jj = 0; jj < 4; ++jj)                     \
      bfr[jj] = LDB(S, KS, jj);                                          \
    _Pragma("unroll") for (int ii = 0; ii < 4; ++ii)                     \
      afr[ii] = LDA(S, KS, ii);                                          \
    __builtin_amdgcn_s_setprio(1);                                       \
    _Pragma("unroll") for (int ii = 0; ii < 4; ++ii)                     \
      _Pragma("unroll") for (int jj = 0; jj < 4; ++jj)                   \
        acc[ii][jj] = __builtin_amdgcn_mfma_f32_16x16x32_bf16(           \
            afr[ii], bfr[jj], acc[ii][jj], 0, 0, 0);                     \
    _Pragma("unroll") for (int ii = 0; ii < 4; ++ii)                     \
      afr[ii] = LDA(S, KS, 4 + ii);                                      \
    _Pragma("unroll") for (int ii = 0; ii < 4; ++ii)                     \
      _Pragma("unroll") for (int jj = 0; jj < 4; ++jj)                   \
        acc[4+ii][jj] = __builtin_amdgcn_mfma_f32_16x16x32_bf16(         \
            afr[ii], bfr[jj], acc[4+ii][jj], 0, 0, 0);                   \
    __builtin_amdgcn_s_setprio(0);                                       \
  } while (0)

  // ---- prologue: A slots (0,0)(0,1)(1,0) via temp regs; B k0/k32/k64;
  // pending pa <- k96 (Q0's AWRITE(1,1)); B(1,1) staged in Q0. ----
  {
    f32x4 t00 = *(const f32x4*)(gxA0 + 0),  t01 = *(const f32x4*)(gxA0 + 4);
    f32x4 t02 = *(const f32x4*)(gxA1 + 0),  t03 = *(const f32x4*)(gxA1 + 4);
    f32x4 t10 = *(const f32x4*)(gxA0 + 32), t11 = *(const f32x4*)(gxA0 + 36);
    f32x4 t12 = *(const f32x4*)(gxA1 + 32), t13 = *(const f32x4*)(gxA1 + 36);
    f32x4 t20 = *(const f32x4*)(gxA0 + 64), t21 = *(const f32x4*)(gxA0 + 68);
    f32x4 t22 = *(const f32x4*)(gxA1 + 64), t23 = *(const f32x4*)(gxA1 + 68);
    pa0 = t00; pa1 = t01; pa2 = t02; pa3 = t03; AWRITE(0, 0);
    pa0 = t10; pa1 = t11; pa2 = t12; pa3 = t13; AWRITE(0, 1);
    pa0 = t20; pa1 = t21; pa2 = t22; pa3 = t23; AWRITE(1, 0);
  }
  AISSUE(96);
  STAGE_B(0, 0, 0); STAGE_B(0, 0, 1); STAGE_B(1, 1, 0);
  WAITV(4);                         // drain B(0,0) (leaves B(0,1),B(1,0))
  LGKM0();                          // A ds_writes visible
  CFENCE();
  __builtin_amdgcn_s_barrier();

  for (int j = 0; j < NI; ++j) {
    const int t1 = 2 * j + 1, ta = 2 * j + 2, tb = 2 * j + 3;
    // Q0: reads (0,0); writes (1,1) [t1 k32]; stages B(1,1); issues A (0,0)'
    AWRITE(1, 1); STAGE_B(t1, 1, 1); AISSUE(KOF(ta));
    QCOMPUTE(0, 0);
    LGKM0(); CFENCE(); __builtin_amdgcn_s_barrier();
    // Q1: reads (0,1); writes (0,0)'; stages B(0,0)'; issues A (0,1)'
    AWRITE(0, 0); STAGE_B(ta, 0, 0); AISSUE(KOF(ta) + 32);
    QCOMPUTE(0, 1);
    LGKM0(); CFENCE(); __builtin_amdgcn_s_barrier();
    // Q2: reads (1,0); writes (0,1)'; stages B(0,1)'; issues A (1,0)'
    AWRITE(0, 1); STAGE_B(ta, 0, 1); AISSUE(KOF(tb));
    QCOMPUTE(1, 0);
    LGKM0(); CFENCE(); __builtin_amdgcn_s_barrier();
    // Q3: reads (1,1); writes (1,0)'; stages B(1,0)'; issues A (1,1)'
    AWRITE(1, 0); STAGE_B(tb, 1, 0); AISSUE(KOF(tb) + 32);
    QCOMPUTE(1, 1);
    LGKM0(); CFENCE(); __builtin_amdgcn_s_barrier();
  }

  // drain stray tail loads (clamped stages) before panel reuse
  WAITV(0);
  LGKM0();
  CFENCE();
  __builtin_amdgcn_s_barrier();

  // ---- epilogue: relu + J=30 mean pool via padded f32 [256][65] panel ----
  float* panel = (float*)smem;      // 66560 B <= 128 KB
  const int q4 = (lane >> 4) * 4;
#pragma unroll 1
  for (int c = 0; c < 4; ++c) {
    if (wc == c) {
#pragma unroll
      for (int i = 0; i < 8; ++i)
#pragma unroll
        for (int jj = 0; jj < 4; ++jj)
#pragma unroll
          for (int r = 0; r < 4; ++r)
            panel[(wr * 128 + i * 16 + q4 + r) * 65 + jj * 16 + fr] =
                fmaxf(acc[i][jj][r], 0.f);
    }
    __builtin_amdgcn_s_barrier();
    CFENCE();
    {
      int col = tid & 63;
      int s = tid >> 6;
      float sum = 0.f;
#pragma unroll
      for (int r = 0; r < 30; ++r) sum += panel[(s * 30 + r) * 65 + col];
      int gseg = by * 8 + s;
      int gcol = bn0 + c * 64 + col;
      feat[(size_t)gseg * 2048 + gcol] = f2bf(sum * (1.f / 30.f));
    }
    CFENCE();
    __builtin_amdgcn_s_barrier();
  }
#undef QCOMPUTE
#undef LDA
#undef LDB
#undef AISSUE
#undef AWRITE
#undef STAGE_B
#undef KOF
}

// ---------------------------------------------------------------------------
// 128x128 kernel: GEMM2 (MODE 2) and the no-workspace fallback (MODE 0).
// ---------------------------------------------------------------------------
#define BM 128
#define BN 128
#define BK 64

template<int MODE>
__global__ __launch_bounds__(256, 2)
void gemm_bt(const void* __restrict__ Ap, const void* __restrict__ Bp,
             void* __restrict__ Cp, int Mv, int Nv, int K, int mstep) {
  constexpr int LDK = (MODE == 0) ? 72 : 64;
  __shared__ __align__(16) unsigned short smem[2 * BM * LDK];
  unsigned short* As = smem;
  unsigned short* Bs = smem + BM * LDK;
  float* Cs = (float*)smem;

  const int tid = threadIdx.x;
  const int lane = tid & 63;
  const int w = tid >> 6;
  const int wr = w >> 1, wc = w & 1;
  const int bm0 = blockIdx.y * mstep;
  const int bn0 = blockIdx.x * BN;

  f32x4 acc[4][4];
#pragma unroll
  for (int i = 0; i < 4; ++i)
#pragma unroll
    for (int j = 0; j < 4; ++j) acc[i][j] = (f32x4){0.f, 0.f, 0.f, 0.f};

  const int fr = lane & 15;
  const int ko = (lane >> 4) * 8;

  for (int kt = 0; kt < K; kt += BK) {
    __syncthreads();
    if constexpr (MODE == 0) {
      const float* A = (const float*)Ap;
      const float* B = (const float*)Bp;
      const int r0 = tid >> 4, kq = tid & 15;
#pragma unroll
      for (int i = 0; i < 8; ++i) {
        int row = i * 16 + r0;
        {
          int gm = bm0 + row;
          f32x4 v = {0.f, 0.f, 0.f, 0.f};
          if (gm < Mv) v = *(const f32x4*)(A + (size_t)gm * K + kt + kq * 4);
          *(unsigned long long*)(As + row * LDK + kq * 4) = pack4(v);
        }
        {
          int gn = bn0 + row;
          f32x4 v = {0.f, 0.f, 0.f, 0.f};
          if (gn < Nv) v = *(const f32x4*)(B + (size_t)gn * K + kt + kq * 4);
          *(unsigned long long*)(Bs + row * LDK + kq * 4) = pack4(v);
        }
      }
    } else {
      const unsigned short* A = (const unsigned short*)Ap;
      const unsigned short* B = (const unsigned short*)Bp;
      const int rsub = lane >> 3;
      const int k8 = (((lane & 7) ^ (lane >> 3)) * 8);
#pragma unroll
      for (int j = 0; j < 4; ++j) {
        int g = w * 4 + j;
        int row = g * 8 + rsub;
        int gm = bm0 + row; if (gm >= Mv) gm = Mv - 1;
        gload_lds16(A + (size_t)gm * K + kt + k8, As + g * 512);
        int gn = bn0 + row; if (gn >= Nv) gn = Nv - 1;
        gload_lds16(B + (size_t)gn * K + kt + k8, Bs + g * 512);
      }
    }
    __syncthreads();
#pragma unroll
    for (int kk = 0; kk < 2; ++kk) {
      const int coffA = (MODE == 0) ? (kk * 32 + ko)
                                    : ((((kk << 2) | (lane >> 4)) ^ (fr & 7)) * 8);
      short8 af[4], bfr[4];
#pragma unroll
      for (int i = 0; i < 4; ++i)
        af[i] = *(const short8*)(As + (wr * 64 + i * 16 + fr) * LDK + coffA);
#pragma unroll
      for (int i = 0; i < 4; ++i)
        bfr[i] = *(const short8*)(Bs + (wc * 64 + i * 16 + fr) * LDK + coffA);
#pragma unroll
      for (int i = 0; i < 4; ++i)
#pragma unroll
        for (int j = 0; j < 4; ++j)
          acc[i][j] = __builtin_amdgcn_mfma_f32_16x16x32_bf16(af[i], bfr[j], acc[i][j], 0, 0, 0);
    }
  }
  __syncthreads();

  if constexpr (MODE != 2) {
    unsigned short* feat = (unsigned short*)Cp;
    const int cr0 = (lane >> 4) * 4;
#pragma unroll
    for (int half = 0; half < 2; ++half) {
      if (wc == half) {
#pragma unroll
        for (int i = 0; i < 4; ++i)
#pragma unroll
          for (int j = 0; j < 4; ++j)
#pragma unroll
            for (int r = 0; r < 4; ++r)
              Cs[(wr * 64 + i * 16 + cr0 + r) * 64 + j * 16 + fr] =
                  fmaxf(acc[i][j][r], 0.f);
      }
      __syncthreads();
      {
        int col = tid & 63;
        int s = tid >> 6;
        float sum = 0.f;
#pragma unroll
        for (int r = 0; r < 30; ++r) sum += Cs[(s * 30 + r) * 64 + col];
        int gseg = blockIdx.y * 4 + s;
        int gcol = bn0 + half * 64 + col;
        feat[(size_t)gseg * 2048 + gcol] = f2bf(sum * (1.f / 30.f));
      }
      __syncthreads();
    }
  } else {
    float* out = (float*)Cp;
    const int cr0 = (lane >> 4) * 4;
#pragma unroll
    for (int i = 0; i < 4; ++i)
#pragma unroll
      for (int j = 0; j < 4; ++j)
#pragma unroll
        for (int r = 0; r < 4; ++r) {
          int gm = bm0 + wr * 64 + i * 16 + cr0 + r;
          int gn = bn0 + wc * 64 + j * 16 + fr;
          if (gm < Mv && gn < Nv) out[(size_t)gm * Nv + gn] = acc[i][j][r];
        }
  }
}

extern "C" void kernel_launch(void* const* d_in, const int* in_sizes, int n_in,
                              void* d_out, int out_size, void* d_ws, size_t ws_size,
                              hipStream_t stream) {
  const float* x    = (const float*)d_in[0];
  const float* W1   = (const float*)d_in[2];
  const float* Wlin = (const float*)d_in[4];
  float* out = (float*)d_out;

  const int T = 60000, DIN = 1024, E = 2048, C = 1000, S = 2000;
  char* ws = (char*)d_ws;
  const size_t off_feat = 0;
  const size_t off_wsum = (size_t)S * E * 2;
  const size_t off_w1b  = off_wsum + (size_t)C * E * 2;
  const size_t need_full = off_w1b + (size_t)E * DIN * 2;  // ~16.5 MB

  unsigned short* feat = (unsigned short*)(ws + off_feat);
  unsigned short* wsum = (unsigned short*)(ws + off_wsum);

  prep_wsum<<<dim3((C * E / 4 + 255) / 256), dim3(256), 0, stream>>>(Wlin, wsum);

  if (ws_size >= need_full) {
    unsigned short* w1b = (unsigned short*)(ws + off_w1b);
    int nw4 = E * DIN / 4;
    cvt_f32_bf16<<<dim3((nw4 + 255) / 256), dim3(256), 0, stream>>>(W1, w1b, nw4);
    gemm256_pool_fA<<<dim3(2000), dim3(512), 0, stream>>>(x, w1b, feat, T, DIN);
  } else {
    gemm_bt<0><<<dim3(16, 500), dim3(256), 0, stream>>>(x, W1, feat, T, E, DIN, 120);
  }

  gemm_bt<2><<<dim3(8, 16), dim3(256), 0, stream>>>(feat, wsum, out, S, C, E, 128);
}

// Round 13
// 379.946 us; speedup vs baseline: 1.0964x; 1.0964x over previous
//
#include <hip/hip_runtime.h>
#include <hip/hip_bf16.h>

// Classifier_69818988363910:
//   F = mean_pool_J30(relu(x @ W1^T))                [2000, 2048]
//   logits = F @ (Wlin[:, :2048]+Wlin[:, 2048:])^T   [2000, 1000]
// (y, W2 are dead per the reference's own bug; features2 == features)

typedef __attribute__((ext_vector_type(4))) float f32x4;
typedef __attribute__((ext_vector_type(8))) short short8;

__device__ __forceinline__ unsigned short f2bf(float f) {
  unsigned int u = __float_as_uint(f);
  unsigned int r = (u + 0x7fffu + ((u >> 16) & 1u)) >> 16;
  return (unsigned short)r;
}

__device__ __forceinline__ unsigned long long pack4(f32x4 v) {
  return (unsigned long long)f2bf(v.x)
       | ((unsigned long long)f2bf(v.y) << 16)
       | ((unsigned long long)f2bf(v.z) << 32)
       | ((unsigned long long)f2bf(v.w) << 48);
}

__device__ __forceinline__ void gload_lds16(const unsigned short* gp, unsigned short* lp) {
  __builtin_amdgcn_global_load_lds((const __attribute__((address_space(1))) void*)gp,
                                   (__attribute__((address_space(3))) void*)lp, 16, 0, 0);
}

__global__ void cvt_f32_bf16(const float* __restrict__ src,
                             unsigned short* __restrict__ dst, int n4) {
  int i = blockIdx.x * 256 + threadIdx.x;
  if (i >= n4) return;
  f32x4 v = *(const f32x4*)(src + (size_t)i * 4);
  *(unsigned long long*)(dst + (size_t)i * 4) = pack4(v);
}

__global__ void prep_wsum(const float* __restrict__ wlin,
                          unsigned short* __restrict__ dst) {
  int i = blockIdx.x * 256 + threadIdx.x;
  if (i >= 1000 * 512) return;
  int c = i >> 9, f4 = i & 511;
  const float* p0 = wlin + (size_t)c * 4096 + f4 * 4;
  f32x4 a = *(const f32x4*)p0;
  f32x4 b = *(const f32x4*)(p0 + 2048);
  f32x4 s = a + b;
  *(unsigned long long*)(dst + (size_t)c * 2048 + f4 * 4) = pack4(s);
}

// ---------------------------------------------------------------------------
// GEMM1: 256x256 tile, 4-Q schedule (one barrier + 32 MFMA per Q), BK=64 as
// 2 K-halves, 2 dbuf slot-pairs per matrix (128 KB), gload_lds staging for
// BOTH operands (R9/R12 proved reg-staging A regresses: FIFO vmcnt collapses
// prefetch depth), R3-form swizzle (R10-measured conflict fix).
// Uniform ledger: Q_q reads slot-pair P_q = {(0,0),(0,1),(1,0),(1,1)}[q],
// stages full A+B pair P_{(q+3)%4} for global K-half h+3 (3-Q prefetch
// ~4000cy >> 900cy HBM). Trailing WAITV(8) every Q: after the Q's 4-load
// stage there are 12 outstanding; draining to 8 lands the pair needed next Q.
// Slot overwrites are >=1 barrier after their last reader. IH1 A-reads are
// independent of IH0 MFMAs -> compiler overlaps them (the 16-MFMA phases
// could not express this).
// ---------------------------------------------------------------------------
#define WAITV(n) asm volatile("s_waitcnt vmcnt(" #n ")" ::: "memory")
#define CFENCE() asm volatile("" ::: "memory")

__global__ __launch_bounds__(512, 2)
void gemm256_pool(const unsigned short* __restrict__ A,
                  const unsigned short* __restrict__ B,
                  unsigned short* __restrict__ feat,
                  int Mv, int K) {
  __shared__ __align__(16) unsigned short smem[65536];  // 128 KB

  const int tid = threadIdx.x;
  const int lane = tid & 63;
  const int w = tid >> 6;          // 0..7
  const int wr = w >> 2;           // 0..1  (M half)
  const int wc = w & 3;            // 0..3  (N quarter)

  // XCD-chunked bijective swizzle: 2000 blocks, 8 XCDs, 250 each.
  const int bid = blockIdx.x;
  const int swz = (bid & 7) * 250 + (bid >> 3);
  const int by = swz >> 3;         // 0..249  M-block
  const int bx = swz & 7;          // 0..7    N-block
  const int bm0 = by * 240;
  const int bn0 = bx * 256;
  const int NT2 = K >> 6;          // K-steps of 64 (=16)
  const int NI = NT2 >> 1;         // iterations (=8)

  // staging: lane covers row base+(lane>>2), phys chunk lane&3.
  // logical k-chunk = (lane&3) ^ ((row>>1)&3) = (lane&3) ^ ((lane>>3)&3).
  const int kslot = (((lane & 3) ^ ((lane >> 3) & 3)) * 8);
  int rA0 = bm0 + w * 32 + 0 + (lane >> 2);  if (rA0 >= Mv) rA0 = Mv - 1;
  int rA1 = bm0 + w * 32 + 16 + (lane >> 2); if (rA1 >= Mv) rA1 = Mv - 1;
  const int rB0 = bn0 + w * 32 + 0 + (lane >> 2);
  const int rB1 = bn0 + w * 32 + 16 + (lane >> 2);
  const unsigned short* gA0 = A + (size_t)rA0 * K + kslot;
  const unsigned short* gA1 = A + (size_t)rA1 * K + kslot;
  const unsigned short* gB0 = B + (size_t)rB0 * K + kslot;
  const unsigned short* gB1 = B + (size_t)rB1 * K + kslot;

// slots: A half (S,KS) at ((S)*2+(KS))*8192 shorts; B at +32768
#define KOF(tt) ((size_t)(((tt) < NT2) ? (tt) : (NT2 - 1)) * 64)
#define STAGE_A(tt, S, KS) do {                                          \
    const size_t _ko = KOF(tt) + (KS) * 32;                              \
    gload_lds16(gA0 + _ko, smem + ((S)*2+(KS))*8192 + w * 1024);         \
    gload_lds16(gA1 + _ko, smem + ((S)*2+(KS))*8192 + w * 1024 + 512);   \
  } while (0)
#define STAGE_B(tt, S, KS) do {                                          \
    const size_t _ko = KOF(tt) + (KS) * 32;                              \
    gload_lds16(gB0 + _ko, smem + 32768 + ((S)*2+(KS))*8192 + w * 1024); \
    gload_lds16(gB1 + _ko, smem + 32768 + ((S)*2+(KS))*8192 + w * 1024 + 512); \
  } while (0)

  f32x4 acc[8][4];
#pragma unroll
  for (int i = 0; i < 8; ++i)
#pragma unroll
    for (int j = 0; j < 4; ++j) acc[i][j] = (f32x4){0.f, 0.f, 0.f, 0.f};

  // fragment reads: row R (stride 32 shorts), phys chunk = q ^ ((fr>>1)&3)
  const int fr = lane & 15;
  const int qa8 = (((lane >> 4) ^ ((fr >> 1) & 3)) * 8);
#define LDA(S, KS, I) (*(const short8*)(smem + ((S)*2+(KS))*8192 +       \
    (wr * 128 + (I) * 16 + fr) * 32 + qa8))
#define LDB(S, KS, J) (*(const short8*)(smem + 32768 + ((S)*2+(KS))*8192 + \
    (wc * 64 + (J) * 16 + fr) * 32 + qa8))

  // One Q: stage pair for h+3 (early issue), read pair P_q (12 ds_read),
  // 32 MFMA (IH1 A-reads overlap IH0 MFMAs), WAITV(8), barrier.
#define QPHASE(S, KS, tt, Ss, KSs) do {                                  \
    STAGE_A(tt, Ss, KSs); STAGE_B(tt, Ss, KSs);                          \
    short8 bfr[4], afr0[4], afr1[4];                                     \
    _Pragma("unroll") for (int jj = 0; jj < 4; ++jj)                     \
      bfr[jj] = LDB(S, KS, jj);                                          \
    _Pragma("unroll") for (int ii = 0; ii < 4; ++ii)                     \
      afr0[ii] = LDA(S, KS, ii);                                         \
    _Pragma("unroll") for (int ii = 0; ii < 4; ++ii)                     \
      afr1[ii] = LDA(S, KS, 4 + ii);                                     \
    __builtin_amdgcn_s_setprio(1);                                       \
    _Pragma("unroll") for (int ii = 0; ii < 4; ++ii)                     \
      _Pragma("unroll") for (int jj = 0; jj < 4; ++jj)                   \
        acc[ii][jj] = __builtin_amdgcn_mfma_f32_16x16x32_bf16(           \
            afr0[ii], bfr[jj], acc[ii][jj], 0, 0, 0);                    \
    _Pragma("unroll") for (int ii = 0; ii < 4; ++ii)                     \
      _Pragma("unroll") for (int jj = 0; jj < 4; ++jj)                   \
        acc[4+ii][jj] = __builtin_amdgcn_mfma_f32_16x16x32_bf16(         \
            afr1[ii], bfr[jj], acc[4+ii][jj], 0, 0, 0);                  \
    __builtin_amdgcn_s_setprio(0);                                       \
    CFENCE();                                                            \
    WAITV(8);                                                            \
    CFENCE();                                                            \
    __builtin_amdgcn_s_barrier();                                        \
  } while (0)

  // ---- prologue: stage pairs (0,0),(0,1),(1,0) = 12 loads, FIFO order ----
  STAGE_A(0, 0, 0); STAGE_B(0, 0, 0);
  STAGE_A(0, 0, 1); STAGE_B(0, 0, 1);
  STAGE_A(1, 1, 0); STAGE_B(1, 1, 0);
  WAITV(8);                         // (0,0) pair landed
  CFENCE();
  __builtin_amdgcn_s_barrier();

  for (int j = 0; j < NI; ++j) {
    const int t1 = 2 * j + 1, ta = 2 * j + 2, tb = 2 * j + 3;
    QPHASE(0, 0, t1, 1, 1);   // Q0: reads (0,0)=t0k0;  stages (1,1)<-t1 k32
    QPHASE(0, 1, ta, 0, 0);   // Q1: reads (0,1)=t0k32; stages (0,0)<-ta k0
    QPHASE(1, 0, ta, 0, 1);   // Q2: reads (1,0)=t1k0;  stages (0,1)<-ta k32
    QPHASE(1, 1, tb, 1, 0);   // Q3: reads (1,1)=t1k32; stages (1,0)<-tb k0
  }

  // drain stray clamped tail stages before panel reuse
  WAITV(0);
  CFENCE();
  __builtin_amdgcn_s_barrier();

  // ---- epilogue: relu + J=30 mean pool via padded f32 [256][65] panel ----
  float* panel = (float*)smem;      // 66560 B <= 128 KB
  const int q4 = (lane >> 4) * 4;
#pragma unroll 1
  for (int c = 0; c < 4; ++c) {
    if (wc == c) {
#pragma unroll
      for (int i = 0; i < 8; ++i)
#pragma unroll
        for (int jj = 0; jj < 4; ++jj)
#pragma unroll
          for (int r = 0; r < 4; ++r)
            panel[(wr * 128 + i * 16 + q4 + r) * 65 + jj * 16 + fr] =
                fmaxf(acc[i][jj][r], 0.f);
    }
    __builtin_amdgcn_s_barrier();
    CFENCE();
    {
      int col = tid & 63;
      int s = tid >> 6;
      float sum = 0.f;
#pragma unroll
      for (int r = 0; r < 30; ++r) sum += panel[(s * 30 + r) * 65 + col];
      int gseg = by * 8 + s;
      int gcol = bn0 + c * 64 + col;
      feat[(size_t)gseg * 2048 + gcol] = f2bf(sum * (1.f / 30.f));
    }
    CFENCE();
    __builtin_amdgcn_s_barrier();
  }
#undef QPHASE
#undef LDA
#undef LDB
#undef STAGE_A
#undef STAGE_B
#undef KOF
}

// ---------------------------------------------------------------------------
// 128x128 kernel: GEMM2 (MODE 2) and the no-workspace fallback (MODE 0).
// ---------------------------------------------------------------------------
#define BM 128
#define BN 128
#define BK 64

template<int MODE>
__global__ __launch_bounds__(256, 2)
void gemm_bt(const void* __restrict__ Ap, const void* __restrict__ Bp,
             void* __restrict__ Cp, int Mv, int Nv, int K, int mstep) {
  constexpr int LDK = (MODE == 0) ? 72 : 64;
  __shared__ __align__(16) unsigned short smem[2 * BM * LDK];
  unsigned short* As = smem;
  unsigned short* Bs = smem + BM * LDK;
  float* Cs = (float*)smem;

  const int tid = threadIdx.x;
  const int lane = tid & 63;
  const int w = tid >> 6;
  const int wr = w >> 1, wc = w & 1;
  const int bm0 = blockIdx.y * mstep;
  const int bn0 = blockIdx.x * BN;

  f32x4 acc[4][4];
#pragma unroll
  for (int i = 0; i < 4; ++i)
#pragma unroll
    for (int j = 0; j < 4; ++j) acc[i][j] = (f32x4){0.f, 0.f, 0.f, 0.f};

  const int fr = lane & 15;
  const int ko = (lane >> 4) * 8;

  for (int kt = 0; kt < K; kt += BK) {
    __syncthreads();
    if constexpr (MODE == 0) {
      const float* A = (const float*)Ap;
      const float* B = (const float*)Bp;
      const int r0 = tid >> 4, kq = tid & 15;
#pragma unroll
      for (int i = 0; i < 8; ++i) {
        int row = i * 16 + r0;
        {
          int gm = bm0 + row;
          f32x4 v = {0.f, 0.f, 0.f, 0.f};
          if (gm < Mv) v = *(const f32x4*)(A + (size_t)gm * K + kt + kq * 4);
          *(unsigned long long*)(As + row * LDK + kq * 4) = pack4(v);
        }
        {
          int gn = bn0 + row;
          f32x4 v = {0.f, 0.f, 0.f, 0.f};
          if (gn < Nv) v = *(const f32x4*)(B + (size_t)gn * K + kt + kq * 4);
          *(unsigned long long*)(Bs + row * LDK + kq * 4) = pack4(v);
        }
      }
    } else {
      const unsigned short* A = (const unsigned short*)Ap;
      const unsigned short* B = (const unsigned short*)Bp;
      const int rsub = lane >> 3;
      const int k8 = (((lane & 7) ^ (lane >> 3)) * 8);
#pragma unroll
      for (int j = 0; j < 4; ++j) {
        int g = w * 4 + j;
        int row = g * 8 + rsub;
        int gm = bm0 + row; if (gm >= Mv) gm = Mv - 1;
        gload_lds16(A + (size_t)gm * K + kt + k8, As + g * 512);
        int gn = bn0 + row; if (gn >= Nv) gn = Nv - 1;
        gload_lds16(B + (size_t)gn * K + kt + k8, Bs + g * 512);
      }
    }
    __syncthreads();
#pragma unroll
    for (int kk = 0; kk < 2; ++kk) {
      const int coffA = (MODE == 0) ? (kk * 32 + ko)
                                    : ((((kk << 2) | (lane >> 4)) ^ (fr & 7)) * 8);
      short8 af[4], bfr[4];
#pragma unroll
      for (int i = 0; i < 4; ++i)
        af[i] = *(const short8*)(As + (wr * 64 + i * 16 + fr) * LDK + coffA);
#pragma unroll
      for (int i = 0; i < 4; ++i)
        bfr[i] = *(const short8*)(Bs + (wc * 64 + i * 16 + fr) * LDK + coffA);
#pragma unroll
      for (int i = 0; i < 4; ++i)
#pragma unroll
        for (int j = 0; j < 4; ++j)
          acc[i][j] = __builtin_amdgcn_mfma_f32_16x16x32_bf16(af[i], bfr[j], acc[i][j], 0, 0, 0);
    }
  }
  __syncthreads();

  if constexpr (MODE != 2) {
    unsigned short* feat = (unsigned short*)Cp;
    const int cr0 = (lane >> 4) * 4;
#pragma unroll
    for (int half = 0; half < 2; ++half) {
      if (wc == half) {
#pragma unroll
        for (int i = 0; i < 4; ++i)
#pragma unroll
          for (int j = 0; j < 4; ++j)
#pragma unroll
            for (int r = 0; r < 4; ++r)
              Cs[(wr * 64 + i * 16 + cr0 + r) * 64 + j * 16 + fr] =
                  fmaxf(acc[i][j][r], 0.f);
      }
      __syncthreads();
      {
        int col = tid & 63;
        int s = tid >> 6;
        float sum = 0.f;
#pragma unroll
        for (int r = 0; r < 30; ++r) sum += Cs[(s * 30 + r) * 64 + col];
        int gseg = blockIdx.y * 4 + s;
        int gcol = bn0 + half * 64 + col;
        feat[(size_t)gseg * 2048 + gcol] = f2bf(sum * (1.f / 30.f));
      }
      __syncthreads();
    }
  } else {
    float* out = (float*)Cp;
    const int cr0 = (lane >> 4) * 4;
#pragma unroll
    for (int i = 0; i < 4; ++i)
#pragma unroll
      for (int j = 0; j < 4; ++j)
#pragma unroll
        for (int r = 0; r < 4; ++r) {
          int gm = bm0 + wr * 64 + i * 16 + cr0 + r;
          int gn = bn0 + wc * 64 + j * 16 + fr;
          if (gm < Mv && gn < Nv) out[(size_t)gm * Nv + gn] = acc[i][j][r];
        }
  }
}

extern "C" void kernel_launch(void* const* d_in, const int* in_sizes, int n_in,
                              void* d_out, int out_size, void* d_ws, size_t ws_size,
                              hipStream_t stream) {
  const float* x    = (const float*)d_in[0];
  const float* W1   = (const float*)d_in[2];
  const float* Wlin = (const float*)d_in[4];
  float* out = (float*)d_out;

  const int T = 60000, DIN = 1024, E = 2048, C = 1000, S = 2000;
  char* ws = (char*)d_ws;
  const size_t off_feat = 0;
  const size_t off_wsum = (size_t)S * E * 2;
  const size_t off_w1b  = off_wsum + (size_t)C * E * 2;
  const size_t off_xb   = off_w1b + (size_t)E * DIN * 2;
  const size_t need_full = off_xb + (size_t)T * DIN * 2;   // ~139.4 MB

  unsigned short* feat = (unsigned short*)(ws + off_feat);
  unsigned short* wsum = (unsigned short*)(ws + off_wsum);

  prep_wsum<<<dim3((C * E / 4 + 255) / 256), dim3(256), 0, stream>>>(Wlin, wsum);

  if (ws_size >= need_full) {
    unsigned short* w1b = (unsigned short*)(ws + off_w1b);
    unsigned short* xb  = (unsigned short*)(ws + off_xb);
    int nx4 = T * DIN / 4;
    cvt_f32_bf16<<<dim3((nx4 + 255) / 256), dim3(256), 0, stream>>>(x, xb, nx4);
    int nw4 = E * DIN / 4;
    cvt_f32_bf16<<<dim3((nw4 + 255) / 256), dim3(256), 0, stream>>>(W1, w1b, nw4);
    gemm256_pool<<<dim3(2000), dim3(512), 0, stream>>>(xb, w1b, feat, T, DIN);
  } else {
    gemm_bt<0><<<dim3(16, 500), dim3(256), 0, stream>>>(x, W1, feat, T, E, DIN, 120);
  }

  gemm_bt<2><<<dim3(8, 16), dim3(256), 0, stream>>>(feat, wsum, out, S, C, E, 128);
}